// Round 1
// baseline (690.783 us; speedup 1.0000x reference)
//
#include <hip/hip_runtime.h>
#include <hip/hip_bf16.h>

// PolynomialADMRSolver: B=4096, N=32, D=1024, fp32.
//   wn[b,d]  = sum_n adj[b,n] * neigh[b,n,d]
//   x[b,d]   = states[b,d] * (wn[b,d] + valence[b])
//   out[b,d] = (x^2 + x^3 + x^5 + x^7) / 4
//
// Memory-bound: neighbor_states (512 MiB) dominates. One block per b,
// 256 threads x float4 => 1024 d per block, fully coalesced 16B/lane loads.

#define B_DIM 4096
#define N_DIM 32
#define D_DIM 1024
#define D4 (D_DIM / 4)   // 256 float4 per row == blockDim.x

__device__ __forceinline__ float poly_facets(float x) {
    // (x^2 + x^3 + x^5 + x^7) * 0.25
    float x2 = x * x;
    float x3 = x2 * x;
    float x5 = x3 * x2;
    float x7 = x5 * x2;
    return 0.25f * (x2 + x3 + x5 + x7);
}

__global__ __launch_bounds__(D4) void poly_admr_kernel(
        const float* __restrict__ states,    // [B, D]
        const float* __restrict__ neigh,     // [B, N, D]
        const float* __restrict__ adj,       // [B, N]
        const float* __restrict__ valence,   // [B]
        float* __restrict__ out)             // [B, D]
{
    const int b = blockIdx.x;
    const int t = threadIdx.x;               // 0..255, owns float4 slot t

    __shared__ float w[N_DIM];
    if (t < N_DIM) w[t] = adj[(size_t)b * N_DIM + t];
    __syncthreads();

    const float val = valence[b];

    const float4* nptr = (const float4*)(neigh + (size_t)b * N_DIM * D_DIM);
    float4 acc = make_float4(0.f, 0.f, 0.f, 0.f);

    #pragma unroll
    for (int n = 0; n < N_DIM; ++n) {
        float4 v = nptr[(size_t)n * D4 + t];
        float wn = w[n];
        acc.x = fmaf(wn, v.x, acc.x);
        acc.y = fmaf(wn, v.y, acc.y);
        acc.z = fmaf(wn, v.z, acc.z);
        acc.w = fmaf(wn, v.w, acc.w);
    }

    float4 s = ((const float4*)(states + (size_t)b * D_DIM))[t];

    float4 o;
    o.x = poly_facets(s.x * (acc.x + val));
    o.y = poly_facets(s.y * (acc.y + val));
    o.z = poly_facets(s.z * (acc.z + val));
    o.w = poly_facets(s.w * (acc.w + val));

    ((float4*)(out + (size_t)b * D_DIM))[t] = o;
}

extern "C" void kernel_launch(void* const* d_in, const int* in_sizes, int n_in,
                              void* d_out, int out_size, void* d_ws, size_t ws_size,
                              hipStream_t stream) {
    const float* states  = (const float*)d_in[0];   // [B, D]
    const float* neigh   = (const float*)d_in[1];   // [B, N, D]
    const float* adj     = (const float*)d_in[2];   // [B, N]
    const float* valence = (const float*)d_in[3];   // [B]
    float* out = (float*)d_out;

    poly_admr_kernel<<<dim3(B_DIM), dim3(D4), 0, stream>>>(
        states, neigh, adj, valence, out);
}

// Round 3
// 660.878 us; speedup vs baseline: 1.0453x; 1.0453x over previous
//
#include <hip/hip_runtime.h>
#include <hip/hip_bf16.h>

// PolynomialADMRSolver: B=4096, N=32, D=1024, fp32.
//   wn[b,d]  = sum_n adj[b,n] * neigh[b,n,d]
//   x[b,d]   = states[b,d] * (wn[b,d] + valence[b])
//   out[b,d] = (x^2 + x^3 + x^5 + x^7) / 4
//
// Memory-bound streaming: neigh (512 MiB) read once, no reuse.
// One block per b, 256 threads x float4, fully coalesced.
// R3: native ext_vector float4 (HIP float4 struct rejected by the
// nontemporal builtins); launch_bounds(256,4); nontemporal ld/st;
// wave-uniform scalar adjacency loads (s_load broadcast, no LDS).

#define B_DIM 4096
#define N_DIM 32
#define D_DIM 1024
#define D4 (D_DIM / 4)   // 256 float4 slots per row == blockDim.x

typedef float f32x4 __attribute__((ext_vector_type(4)));

__device__ __forceinline__ float poly_facets(float x) {
    // (x^2 + x^3 + x^5 + x^7) * 0.25
    float x2 = x * x;
    float x3 = x2 * x;
    float x5 = x3 * x2;
    float x7 = x5 * x2;
    return 0.25f * (x2 + x3 + x5 + x7);
}

__global__ __launch_bounds__(D4, 4) void poly_admr_kernel(
        const float* __restrict__ states,    // [B, D]
        const float* __restrict__ neigh,     // [B, N, D]
        const float* __restrict__ adj,       // [B, N]
        const float* __restrict__ valence,   // [B]
        float* __restrict__ out)             // [B, D]
{
    const int b = blockIdx.x;
    const int t = threadIdx.x;               // 0..255

    // Wave-uniform adjacency row -> s_load (scalar cache broadcast).
    const float* __restrict__ adj_row = adj + (size_t)b * N_DIM;
    const float val = valence[b];

    const f32x4* __restrict__ nptr =
        (const f32x4*)(neigh + (size_t)b * N_DIM * D_DIM);

    f32x4 acc = (f32x4){0.f, 0.f, 0.f, 0.f};

    #pragma unroll
    for (int n = 0; n < N_DIM; ++n) {
        f32x4 v = __builtin_nontemporal_load(&nptr[(size_t)n * D4 + t]);
        float wn = adj_row[n];
        acc.x = fmaf(wn, v.x, acc.x);
        acc.y = fmaf(wn, v.y, acc.y);
        acc.z = fmaf(wn, v.z, acc.z);
        acc.w = fmaf(wn, v.w, acc.w);
    }

    f32x4 s = __builtin_nontemporal_load(
        &((const f32x4*)(states + (size_t)b * D_DIM))[t]);

    f32x4 o;
    o.x = poly_facets(s.x * (acc.x + val));
    o.y = poly_facets(s.y * (acc.y + val));
    o.z = poly_facets(s.z * (acc.z + val));
    o.w = poly_facets(s.w * (acc.w + val));

    __builtin_nontemporal_store(o, &((f32x4*)(out + (size_t)b * D_DIM))[t]);
}

extern "C" void kernel_launch(void* const* d_in, const int* in_sizes, int n_in,
                              void* d_out, int out_size, void* d_ws, size_t ws_size,
                              hipStream_t stream) {
    const float* states  = (const float*)d_in[0];   // [B, D]
    const float* neigh   = (const float*)d_in[1];   // [B, N, D]
    const float* adj     = (const float*)d_in[2];   // [B, N]
    const float* valence = (const float*)d_in[3];   // [B]
    float* out = (float*)d_out;

    poly_admr_kernel<<<dim3(B_DIM), dim3(D4), 0, stream>>>(
        states, neigh, adj, valence, out);
}

// Round 4
// 660.741 us; speedup vs baseline: 1.0455x; 1.0002x over previous
//
#include <hip/hip_runtime.h>
#include <hip/hip_bf16.h>

// PolynomialADMRSolver: B=4096, N=32, D=1024, fp32.
//   wn[b,d]  = sum_n adj[b,n] * neigh[b,n,d]
//   x[b,d]   = states[b,d] * (wn[b,d] + valence[b])
//   out[b,d] = (x^2 + x^3 + x^5 + x^7) / 4
//
// Memory-bound streaming (561 MiB/launch, no reuse). R4: two b-rows per
// block (2048 blocks x 256 threads) -> two independent load streams +
// two independent FMA chains per thread (2x MLP), half the blocks.
// Keep: nontemporal ld/st, wave-uniform scalar adj loads, (256,4).

#define B_DIM 4096
#define N_DIM 32
#define D_DIM 1024
#define D4 (D_DIM / 4)   // 256 float4 slots per row == blockDim.x

typedef float f32x4 __attribute__((ext_vector_type(4)));

__device__ __forceinline__ float poly_facets(float x) {
    // (x^2 + x^3 + x^5 + x^7) * 0.25
    float x2 = x * x;
    float x3 = x2 * x;
    float x5 = x3 * x2;
    float x7 = x5 * x2;
    return 0.25f * (x2 + x3 + x5 + x7);
}

__global__ __launch_bounds__(256, 4) void poly_admr_kernel(
        const float* __restrict__ states,    // [B, D]
        const float* __restrict__ neigh,     // [B, N, D]
        const float* __restrict__ adj,       // [B, N]
        const float* __restrict__ valence,   // [B]
        float* __restrict__ out)             // [B, D]
{
    const int b0 = blockIdx.x * 2;
    const int b1 = b0 + 1;
    const int t = threadIdx.x;               // 0..255

    // Wave-uniform adjacency rows -> s_load broadcast, hoisted by unroll.
    const float* __restrict__ adj0 = adj + (size_t)b0 * N_DIM;
    const float* __restrict__ adj1 = adj + (size_t)b1 * N_DIM;
    const float val0 = valence[b0];
    const float val1 = valence[b1];

    const f32x4* __restrict__ np0 =
        (const f32x4*)(neigh + (size_t)b0 * N_DIM * D_DIM);
    const f32x4* __restrict__ np1 =
        (const f32x4*)(neigh + (size_t)b1 * N_DIM * D_DIM);

    f32x4 acc0 = (f32x4){0.f, 0.f, 0.f, 0.f};
    f32x4 acc1 = (f32x4){0.f, 0.f, 0.f, 0.f};

    #pragma unroll
    for (int n = 0; n < N_DIM; ++n) {
        f32x4 v0 = __builtin_nontemporal_load(&np0[(size_t)n * D4 + t]);
        f32x4 v1 = __builtin_nontemporal_load(&np1[(size_t)n * D4 + t]);
        float w0 = adj0[n];
        float w1 = adj1[n];
        acc0.x = fmaf(w0, v0.x, acc0.x);
        acc0.y = fmaf(w0, v0.y, acc0.y);
        acc0.z = fmaf(w0, v0.z, acc0.z);
        acc0.w = fmaf(w0, v0.w, acc0.w);
        acc1.x = fmaf(w1, v1.x, acc1.x);
        acc1.y = fmaf(w1, v1.y, acc1.y);
        acc1.z = fmaf(w1, v1.z, acc1.z);
        acc1.w = fmaf(w1, v1.w, acc1.w);
    }

    f32x4 s0 = __builtin_nontemporal_load(
        &((const f32x4*)(states + (size_t)b0 * D_DIM))[t]);
    f32x4 s1 = __builtin_nontemporal_load(
        &((const f32x4*)(states + (size_t)b1 * D_DIM))[t]);

    f32x4 o0, o1;
    o0.x = poly_facets(s0.x * (acc0.x + val0));
    o0.y = poly_facets(s0.y * (acc0.y + val0));
    o0.z = poly_facets(s0.z * (acc0.z + val0));
    o0.w = poly_facets(s0.w * (acc0.w + val0));
    o1.x = poly_facets(s1.x * (acc1.x + val1));
    o1.y = poly_facets(s1.y * (acc1.y + val1));
    o1.z = poly_facets(s1.z * (acc1.z + val1));
    o1.w = poly_facets(s1.w * (acc1.w + val1));

    __builtin_nontemporal_store(o0, &((f32x4*)(out + (size_t)b0 * D_DIM))[t]);
    __builtin_nontemporal_store(o1, &((f32x4*)(out + (size_t)b1 * D_DIM))[t]);
}

extern "C" void kernel_launch(void* const* d_in, const int* in_sizes, int n_in,
                              void* d_out, int out_size, void* d_ws, size_t ws_size,
                              hipStream_t stream) {
    const float* states  = (const float*)d_in[0];   // [B, D]
    const float* neigh   = (const float*)d_in[1];   // [B, N, D]
    const float* adj     = (const float*)d_in[2];   // [B, N]
    const float* valence = (const float*)d_in[3];   // [B]
    float* out = (float*)d_out;

    poly_admr_kernel<<<dim3(B_DIM / 2), dim3(256), 0, stream>>>(
        states, neigh, adj, valence, out);
}